// Round 4
// baseline (88.082 us; speedup 1.0000x reference)
//
#include <hip/hip_runtime.h>
#include <math.h>

#define N_PTS   2048
#define BLOCK   128    // threads per block
#define NQ      16     // queries per thread -> 2048 queries per block (whole cloud)
#define SLAB    128    // candidates staged per block
#define NSLAB   (N_PTS / SLAB)   // 16

typedef float v2f __attribute__((ext_vector_type(2)));

// Grid: (32 bs, 2 dir, 16 slab) = 1024 blocks, 128 threads.
// LDS holds the slab in SoA-PAIR layout (float2 of two consecutive candidates
// per component) so ds_read_b64 lands in even-aligned VGPR pairs feeding
// v_pk_fma_f32 directly. Per 2 candidates per query: 3 pk_fma + 1 v_min3
// => 2 VALU ops/pair (was 3.5). NQ=16 keeps the LDS pipe (4 b64 / 2 cand)
// below the VALU rate. Partial d^2 = p2 + best stored to a per-slab ws slice.
__global__ __launch_bounds__(BLOCK) void chamfer_min_kernel(
    const float* __restrict__ pred,
    const float* __restrict__ tgt,
    float* __restrict__ ws)
{
    __shared__ v2f shx[SLAB / 2], shy[SLAB / 2], shz[SLAB / 2], shw[SLAB / 2];

    const int bs   = blockIdx.x;   // 0..31
    const int dir  = blockIdx.y;   // 0..1
    const int slab = blockIdx.z;   // 0..15
    const int tid  = threadIdx.x;

    const float* Abase = (dir ? tgt : pred) + (size_t)bs * N_PTS * 3;  // queries
    const float* Bbase = (dir ? pred : tgt) + (size_t)bs * N_PTS * 3;  // candidates

    // Stage: one candidate per thread, scattered into SoA-pair arrays.
    {
        const int j = slab * SLAB + tid;
        const float x = Bbase[3 * j + 0];
        const float y = Bbase[3 * j + 1];
        const float z = Bbase[3 * j + 2];
        ((float*)shx)[tid] = x;
        ((float*)shy)[tid] = y;
        ((float*)shz)[tid] = z;
        ((float*)shw)[tid] = x * x + y * y + z * z;
    }
    __syncthreads();

    // 16 query points per thread; pre-scale by -2, duplicated into both
    // packed halves (compiler may fold via op_sel).
    v2f nx2[NQ], ny2[NQ], nz2[NQ];
    float p2[NQ], best[NQ];
    #pragma unroll
    for (int k = 0; k < NQ; ++k) {
        const int q = tid + BLOCK * k;
        const float px = Abase[3 * q + 0];
        const float py = Abase[3 * q + 1];
        const float pz = Abase[3 * q + 2];
        const float ax = -2.0f * px, ay = -2.0f * py, az = -2.0f * pz;
        nx2[k] = (v2f){ax, ax};
        ny2[k] = (v2f){ay, ay};
        nz2[k] = (v2f){az, az};
        p2[k] = px * px + py * py + pz * pz;
        best[k] = 3.4e38f;
    }

    // Hot loop: 2 candidates per iter via packed fp32 math.
    #pragma unroll 2
    for (int jj = 0; jj < SLAB / 2; ++jj) {
        const v2f tx = shx[jj];
        const v2f ty = shy[jj];
        const v2f tz = shz[jj];
        const v2f tw = shw[jj];
        #pragma unroll
        for (int k = 0; k < NQ; ++k) {
            const v2f v = __builtin_elementwise_fma(nx2[k], tx,
                          __builtin_elementwise_fma(ny2[k], ty,
                          __builtin_elementwise_fma(nz2[k], tz, tw)));
            best[k] = fminf(best[k], fminf(v.x, v.y));   // v_min3_f32
        }
    }

    // Store per-slab partial d^2 (clamped at finalize).
    // Layout: ws[((dir*NSLAB + slab)*32 + bs)*N_PTS + q] -> coalesced.
    float* dst = ws + ((size_t)(dir * NSLAB + slab) * 32 + bs) * N_PTS;
    #pragma unroll
    for (int k = 0; k < NQ; ++k)
        dst[tid + BLOCK * k] = p2[k] + best[k];
}

// For each of 131072 (dir,bs,q) points: min over 16 slab partials, clamp,
// sqrt, block-reduce, one atomicAdd. Grid: 512 blocks x 256 threads.
__global__ __launch_bounds__(256) void chamfer_finalize_kernel(
    const float* __restrict__ ws,
    float* __restrict__ out)
{
    __shared__ float red[4];
    const int i = blockIdx.x * 256 + threadIdx.x;     // 0..131071
    const int dir = i >> 16;                          // 0..1
    const int bsq = i & 0xFFFF;                       // bs*2048+q

    float m = 3.4e38f;
    #pragma unroll
    for (int s = 0; s < NSLAB; ++s)
        m = fminf(m, ws[(size_t)(dir * NSLAB + s) * 65536 + bsq]);
    float d = sqrtf(fmaxf(m, 0.0f));

    for (int off = 32; off > 0; off >>= 1)
        d += __shfl_down(d, off, 64);
    const int tid = threadIdx.x;
    if ((tid & 63) == 0) red[tid >> 6] = d;
    __syncthreads();
    if (tid == 0) {
        const float blk = red[0] + red[1] + red[2] + red[3];
        atomicAdd(out, blk * (1.0f / 65536.0f));  // 1/(B*S*N), N==M
    }
}

extern "C" void kernel_launch(void* const* d_in, const int* in_sizes, int n_in,
                              void* d_out, int out_size, void* d_ws, size_t ws_size,
                              hipStream_t stream) {
    const float* pred = (const float*)d_in[0];
    const float* tgt  = (const float*)d_in[1];
    float* out = (float*)d_out;
    float* ws = (float*)d_ws;   // 2*16*32*2048 floats = 8 MB partial mins

    hipMemsetAsync(out, 0, sizeof(float), stream);

    dim3 grid(32, 2, NSLAB);
    chamfer_min_kernel<<<grid, BLOCK, 0, stream>>>(pred, tgt, ws);

    chamfer_finalize_kernel<<<131072 / 256, 256, 0, stream>>>(ws, out);
}

// Round 5
// 84.028 us; speedup vs baseline: 1.0482x; 1.0482x over previous
//
#include <hip/hip_runtime.h>
#include <math.h>

#define N_PTS   2048
#define BLOCK   256    // threads per block
#define NQ      8      // queries per thread -> 2048 queries per block (whole cloud)
#define SLAB    128    // candidates staged per block
#define NSLAB   (N_PTS / SLAB)   // 16

typedef float v2f __attribute__((ext_vector_type(2)));

// Grid: (32 bs, 2 dir, 16 slab) = 1024 blocks, 256 threads, 4 blocks/CU.
// LDS: slab in SoA-pair layout (float2 of two consecutive candidates per
// component) -> ds_read_b64 into even VGPR pairs feeding v_pk_fma_f32.
// Per 2 candidates per query: 3 pk_fma + 1 v_min3 => 2 VALU ops/pair.
// Cross-slab combine: uint atomicMin on clamped d^2 (float-order==uint-order
// for non-negative floats); ws pre-memset to 0xFF (uint max).
__global__ __launch_bounds__(BLOCK, 4) void chamfer_min_kernel(
    const float* __restrict__ pred,
    const float* __restrict__ tgt,
    unsigned int* __restrict__ wsmin)
{
    __shared__ v2f shx[SLAB / 2], shy[SLAB / 2], shz[SLAB / 2], shw[SLAB / 2];

    const int bs   = blockIdx.x;   // 0..31
    const int dir  = blockIdx.y;   // 0..1
    const int slab = blockIdx.z;   // 0..15
    const int tid  = threadIdx.x;

    const float* Abase = (dir ? tgt : pred) + (size_t)bs * N_PTS * 3;  // queries
    const float* Bbase = (dir ? pred : tgt) + (size_t)bs * N_PTS * 3;  // candidates

    // Stage slab (first 128 threads), SoA with |q|^2 precomputed.
    if (tid < SLAB) {
        const int j = slab * SLAB + tid;
        const float x = Bbase[3 * j + 0];
        const float y = Bbase[3 * j + 1];
        const float z = Bbase[3 * j + 2];
        ((float*)shx)[tid] = x;
        ((float*)shy)[tid] = y;
        ((float*)shz)[tid] = z;
        ((float*)shw)[tid] = x * x + y * y + z * z;
    }
    __syncthreads();

    // 8 query points per thread; pre-scale by -2, splat into packed pairs.
    v2f nx2[NQ], ny2[NQ], nz2[NQ];
    float p2[NQ], best[NQ];
    #pragma unroll
    for (int k = 0; k < NQ; ++k) {
        const int q = tid + BLOCK * k;
        const float px = Abase[3 * q + 0];
        const float py = Abase[3 * q + 1];
        const float pz = Abase[3 * q + 2];
        const float ax = -2.0f * px, ay = -2.0f * py, az = -2.0f * pz;
        nx2[k] = (v2f){ax, ax};
        ny2[k] = (v2f){ay, ay};
        nz2[k] = (v2f){az, az};
        p2[k] = px * px + py * py + pz * pz;
        best[k] = 3.4e38f;
    }

    // Hot loop: 2 candidates/iter via v_pk_fma_f32; min3 folds the pair.
    #pragma unroll 2
    for (int jj = 0; jj < SLAB / 2; ++jj) {
        const v2f tx = shx[jj];
        const v2f ty = shy[jj];
        const v2f tz = shz[jj];
        const v2f tw = shw[jj];
        #pragma unroll
        for (int k = 0; k < NQ; ++k) {
            const v2f v = __builtin_elementwise_fma(nx2[k], tx,
                          __builtin_elementwise_fma(ny2[k], ty,
                          __builtin_elementwise_fma(nz2[k], tz, tw)));
            best[k] = fminf(best[k], fminf(v.x, v.y));   // v_min3_f32
        }
    }

    // Clamp then combine across slabs (uint order == float order when >= 0).
    const int base = (dir * 32 + bs) * N_PTS;
    #pragma unroll
    for (int k = 0; k < NQ; ++k) {
        const float d2 = fmaxf(p2[k] + best[k], 0.0f);
        atomicMin(&wsmin[base + tid + BLOCK * k], __float_as_uint(d2));
    }
}

// 131072 min-d^2 values -> sqrt -> sum/65536 -> out. 128 blocks x 256 thr,
// one float4 per thread, contiguous coalesced reads.
__global__ __launch_bounds__(256) void chamfer_finalize_kernel(
    const float4* __restrict__ wsmin,
    float* __restrict__ out)
{
    __shared__ float red[4];
    const int i = blockIdx.x * 256 + threadIdx.x;
    const float4 t = wsmin[i];
    float s = sqrtf(t.x) + sqrtf(t.y) + sqrtf(t.z) + sqrtf(t.w);

    for (int off = 32; off > 0; off >>= 1)
        s += __shfl_down(s, off, 64);
    const int tid = threadIdx.x;
    if ((tid & 63) == 0) red[tid >> 6] = s;
    __syncthreads();
    if (tid == 0) {
        const float blk = red[0] + red[1] + red[2] + red[3];
        atomicAdd(out, blk * (1.0f / 65536.0f));  // 1/(B*S*N), N==M
    }
}

extern "C" void kernel_launch(void* const* d_in, const int* in_sizes, int n_in,
                              void* d_out, int out_size, void* d_ws, size_t ws_size,
                              hipStream_t stream) {
    const float* pred = (const float*)d_in[0];
    const float* tgt  = (const float*)d_in[1];
    float* out = (float*)d_out;
    unsigned int* wsmin = (unsigned int*)d_ws;   // 131072 uints = 512 KB

    // 0xFF = uint-max: identity for atomicMin. 4B out zeroed for atomicAdd.
    hipMemsetAsync(wsmin, 0xFF, (size_t)131072 * sizeof(unsigned int), stream);
    hipMemsetAsync(out, 0, sizeof(float), stream);

    dim3 grid(32, 2, NSLAB);
    chamfer_min_kernel<<<grid, BLOCK, 0, stream>>>(pred, tgt, wsmin);

    chamfer_finalize_kernel<<<131072 / (256 * 4), 256, 0, stream>>>(
        (const float4*)wsmin, out);
}